// Round 2
// baseline (7836.610 us; speedup 1.0000x reference)
//
#include <hip/hip_runtime.h>
#include <hip/hip_bf16.h>

// Problem dims
#define BB 32
#define SS 128
#define TT 64
#define EE 64
#define HH 512
#define H3 1536
#define VV 32000
#define EHD 576      // E + H (dec0 input width)
#define TD 63        // decoder steps
#define MFC 2048     // padded M for fc GEMM (63*32 = 2016 real rows)

typedef unsigned short u16;
typedef unsigned int   u32;

typedef __attribute__((ext_vector_type(8))) short bf16x8;
typedef __attribute__((ext_vector_type(4))) float f32x4;

__device__ __forceinline__ float bf2f(u16 u){ return __uint_as_float(((u32)u)<<16); }
__device__ __forceinline__ u16 f2bf(float f){
  u32 u = __float_as_uint(f);
  u += 0x7FFFu + ((u>>16)&1u);       // RNE
  return (u16)(u>>16);
}
__device__ __forceinline__ float sigm(float x){ return 1.f/(1.f+__expf(-x)); }
__device__ __forceinline__ float tanh_f(float x){ return 1.f - 2.f/(1.f+__expf(2.f*x)); }

__device__ __forceinline__ void bf8f(uint4 q, float* f){
  f[0]=__uint_as_float(q.x<<16); f[1]=__uint_as_float(q.x&0xFFFF0000u);
  f[2]=__uint_as_float(q.y<<16); f[3]=__uint_as_float(q.y&0xFFFF0000u);
  f[4]=__uint_as_float(q.z<<16); f[5]=__uint_as_float(q.z&0xFFFF0000u);
  f[6]=__uint_as_float(q.w<<16); f[7]=__uint_as_float(q.w&0xFFFF0000u);
}

// ---- dtype-abstracted weight access: BF=true -> bf16 data, BF=false -> fp32 data
template<bool BF>
__device__ __forceinline__ void wload8(const void* base, size_t eoff, float* f){
  if constexpr (BF){
    uint4 q = *(const uint4*)((const u16*)base + eoff);
    bf8f(q, f);
  } else {
    const float4* p = (const float4*)((const float*)base + eoff);
    float4 a = p[0], b = p[1];
    f[0]=a.x; f[1]=a.y; f[2]=a.z; f[3]=a.w;
    f[4]=b.x; f[5]=b.y; f[6]=b.z; f[7]=b.w;
  }
}
template<bool BF>
__device__ __forceinline__ float wld(const void* base, size_t eoff){
  if constexpr (BF) return bf2f(((const u16*)base)[eoff]);
  else              return ((const float*)base)[eoff];
}
// stage 32 weight elements -> LDS as bf16
template<bool BF>
__device__ __forceinline__ void stage32(const void* gbase, size_t eoff, u16* lds){
  if constexpr (BF){
    const uint4* g = (const uint4*)((const u16*)gbase + eoff);
    uint4* l = (uint4*)lds;
    l[0]=g[0]; l[1]=g[1]; l[2]=g[2]; l[3]=g[3];
  } else {
    const float4* g = (const float4*)((const float*)gbase + eoff);
    #pragma unroll
    for(int i=0;i<8;i++){
      float4 v = g[i];
      u16* d = lds + i*4;
      d[0]=f2bf(v.x); d[1]=f2bf(v.y); d[2]=f2bf(v.z); d[3]=f2bf(v.w);
    }
  }
}

// ---------------------------------------------------------------------------
// dtype detector: view first 1024 u16 of fc_W as bf16; genuine bf16 data has
// max|x| ~ 0.25; fp32 data's low mantissa halves have uniform exponent bits ->
// max blows past 16 with certainty. flag=1 -> bf16 world.
__global__ __launch_bounds__(64) void k_detect(const void* w, int* flag){
  int tid = threadIdx.x;
  const u16* p = (const u16*)w;
  float m = 0.f;
  #pragma unroll
  for(int i=0;i<16;i++){
    float v = fabsf(bf2f(p[tid*16+i]));
    m = fmaxf(m, v);
  }
  #pragma unroll
  for(int off=32;off;off>>=1) m = fmaxf(m, __shfl_down(m, off));
  if(tid==0) *flag = (m < 16.f) ? 1 : 0;
}

// ---------------------------------------------------------------------------
// Batched embedding -> input-gate projection
template<bool BF>
__device__ void emb_gi_body(const int* toks, int tstride, const void* emb_tab,
                            const void* W_ih, int wstride, const void* b_ih,
                            float* gi)
{
  int blk = blockIdx.x;
  int jc = blk % 6; int b = (blk/6) % BB; int t = blk/(6*BB);
  int tid = threadIdx.x;
  int tok = toks[b*tstride + t];
  __shared__ float emb[EE];
  if(tid < EE) emb[tid] = wld<BF>(emb_tab, (size_t)tok*EE + tid);
  __syncthreads();
  int j = jc*256 + tid;
  float acc = wld<BF>(b_ih, j);
  size_t roff = (size_t)j*wstride;
  #pragma unroll
  for(int i=0;i<8;i++){
    float f[8]; wload8<BF>(W_ih, roff + i*8, f);
    #pragma unroll
    for(int l=0;l<8;l++) acc += emb[i*8+l]*f[l];
  }
  gi[((size_t)t*BB + b)*H3 + j] = acc;
}
__global__ __launch_bounds__(256) void k_emb_gi(
    const int* flag, const int* toks, int tstride, const void* emb_tab,
    const void* W_ih, int wstride, const void* b_ih, float* gi)
{
  if(*flag) emb_gi_body<true>(toks,tstride,emb_tab,W_ih,wstride,b_ih,gi);
  else      emb_gi_body<false>(toks,tstride,emb_tab,W_ih,wstride,b_ih,gi);
}

// ---------------------------------------------------------------------------
// One encoder GRU step. grid=256 (b=blk>>3, q=blk&7), block=256.
template<bool BF>
__device__ void enc_step_body(const float* hin, float* hout,
                              const void* W_hh, const void* b_hh,
                              const float* gi_t, float* enc_outs, int t,
                              float* h0init, float* h1init)
{
  int b = blockIdx.x >> 3, q = blockIdx.x & 7;
  int tid = threadIdx.x;
  __shared__ float hs[HH];
  __shared__ float red[3][256];
  const float* hrow = hin + b*HH;
  hs[tid] = hrow[tid]; hs[tid+256] = hrow[tid+256];
  __syncthreads();
  int jj = tid >> 2, t4 = tid & 3;
  int j = q*64 + jj;
  int k0 = t4*128;
  float ar=0.f, az=0.f, an=0.f;
  size_t orr = (size_t)j*HH + k0;
  size_t oz = (size_t)(512+j)*HH + k0;
  size_t on = (size_t)(1024+j)*HH + k0;
  #pragma unroll 4
  for(int i=0;i<16;i++){
    float f[8];
    wload8<BF>(W_hh, orr + i*8, f);
    #pragma unroll
    for(int l=0;l<8;l++) ar += hs[k0+i*8+l]*f[l];
    wload8<BF>(W_hh, oz + i*8, f);
    #pragma unroll
    for(int l=0;l<8;l++) az += hs[k0+i*8+l]*f[l];
    wload8<BF>(W_hh, on + i*8, f);
    #pragma unroll
    for(int l=0;l<8;l++) an += hs[k0+i*8+l]*f[l];
  }
  red[0][tid]=ar; red[1][tid]=az; red[2][tid]=an;
  __syncthreads();
  if(t4==0){
    float gr = red[0][tid]+red[0][tid+1]+red[0][tid+2]+red[0][tid+3] + wld<BF>(b_hh, j);
    float gz = red[1][tid]+red[1][tid+1]+red[1][tid+2]+red[1][tid+3] + wld<BF>(b_hh, 512+j);
    float gn = red[2][tid]+red[2][tid+1]+red[2][tid+2]+red[2][tid+3] + wld<BF>(b_hh, 1024+j);
    const float* gib = gi_t + b*H3;
    float r = sigm(gib[j] + gr);
    float z = sigm(gib[512+j] + gz);
    float n = tanh_f(gib[1024+j] + r*gn);
    float hn = (1.f - z)*n + z*hs[j];
    hout[b*HH + j] = hn;
    enc_outs[((size_t)b*SS + t)*HH + j] = hn;
    if(h0init){ h0init[b*HH+j] = hn; h1init[b*HH+j] = hn; }
  }
}
__global__ __launch_bounds__(256) void k_enc_step(
    const int* flag, const float* hin, float* hout,
    const void* W_hh, const void* b_hh, const float* gi_t,
    float* enc_outs, int t, float* h0init, float* h1init)
{
  if(*flag) enc_step_body<true>(hin,hout,W_hh,b_hh,gi_t,enc_outs,t,h0init,h1init);
  else      enc_step_body<false>(hin,hout,W_hh,b_hh,gi_t,enc_outs,t,h0init,h1init);
}

// ---------------------------------------------------------------------------
// P[b,s,j] = attn_W[j, 512:1024] . enc_outs[b,s,:] + attn_b[j]
template<bool BF>
__device__ void attn_proj_body(const float* enc_outs, const void* attn_W,
                               const void* attn_b, float* P)
{
  int blk = blockIdx.x;
  int jc = blk & 1; int s = (blk>>1) & (SS-1); int b = blk >> 8;
  int tid = threadIdx.x;
  __shared__ float es[HH];
  const float* er = enc_outs + ((size_t)b*SS + s)*HH;
  es[tid]=er[tid]; es[tid+256]=er[tid+256];
  __syncthreads();
  int j = jc*256 + tid;
  size_t roff = (size_t)j*1024 + 512;
  float acc = wld<BF>(attn_b, j);
  #pragma unroll 4
  for(int i=0;i<64;i++){
    float f[8]; wload8<BF>(attn_W, roff + i*8, f);
    #pragma unroll
    for(int l=0;l<8;l++) acc += es[i*8+l]*f[l];
  }
  P[((size_t)b*SS+s)*HH + j] = acc;
}
__global__ __launch_bounds__(256) void k_attn_proj(
  const int* flag, const float* enc_outs, const void* attn_W,
  const void* attn_b, float* P)
{
  if(*flag) attn_proj_body<true>(enc_outs, attn_W, attn_b, P);
  else      attn_proj_body<false>(enc_outs, attn_W, attn_b, P);
}

// ---------------------------------------------------------------------------
// A[b,j] = attn_W[j, 0:512] . h1[b,:]
template<bool BF>
__device__ void dec_A_body(const float* h1, const void* attn_W, float* Abuf)
{
  int b = blockIdx.x >> 1, jc = blockIdx.x & 1;
  int tid = threadIdx.x;
  __shared__ float hsr[HH];
  hsr[tid]=h1[b*HH+tid]; hsr[tid+256]=h1[b*HH+tid+256];
  __syncthreads();
  int j = jc*256 + tid;
  size_t roff = (size_t)j*1024;
  float acc = 0.f;
  #pragma unroll 4
  for(int i=0;i<64;i++){
    float f[8]; wload8<BF>(attn_W, roff + i*8, f);
    #pragma unroll
    for(int l=0;l<8;l++) acc += hsr[i*8+l]*f[l];
  }
  Abuf[b*HH + j] = acc;
}
__global__ __launch_bounds__(256) void k_dec_A(
  const int* flag, const float* h1, const void* attn_W, float* Abuf)
{
  if(*flag) dec_A_body<true>(h1, attn_W, Abuf);
  else      dec_A_body<false>(h1, attn_W, Abuf);
}

// ---------------------------------------------------------------------------
// scores + exp + partial softmax-weighted context
template<bool BF>
__device__ void dec_scores_body(const float* Abuf, const float* P,
                                const float* enc_outs, const void* vW,
                                const void* vb, float* Cpart, float* Ssum)
{
  int b = blockIdx.x >> 3, sb = blockIdx.x & 7;
  int tid = threadIdx.x;
  __shared__ float As[HH];
  __shared__ float vs[HH];
  __shared__ float eS[16];
  As[tid]=Abuf[b*HH+tid]; As[tid+256]=Abuf[b*HH+tid+256];
  vs[tid]=wld<BF>(vW, tid); vs[tid+256]=wld<BF>(vW, tid+256);
  __syncthreads();
  int wave = tid>>6, lane = tid&63;
  float vbf = wld<BF>(vb, 0);
  #pragma unroll
  for(int i=0;i<4;i++){
    int s = sb*16 + wave*4 + i;
    const float* Prow = P + ((size_t)b*SS+s)*HH;
    float part = 0.f;
    #pragma unroll
    for(int kk=0;kk<8;kk++){
      int k = lane + kk*64;
      part += vs[k]*tanh_f(As[k]+Prow[k]);
    }
    #pragma unroll
    for(int off=32;off;off>>=1) part += __shfl_down(part, off);
    if(lane==0) eS[wave*4+i] = __expf(part + vbf);
  }
  __syncthreads();
  for(int j=tid;j<HH;j+=256){
    float c = 0.f;
    #pragma unroll 4
    for(int i=0;i<16;i++) c += eS[i]*enc_outs[((size_t)b*SS + sb*16+i)*HH + j];
    Cpart[((size_t)b*8+sb)*HH + j] = c;
  }
  if(tid==0){ float ss=0.f; for(int i=0;i<16;i++) ss+=eS[i]; Ssum[b*8+sb]=ss; }
}
__global__ __launch_bounds__(256) void k_dec_scores(
  const int* flag, const float* Abuf, const float* P, const float* enc_outs,
  const void* vW, const void* vb, float* Cpart, float* Ssum)
{
  if(*flag) dec_scores_body<true>(Abuf,P,enc_outs,vW,vb,Cpart,Ssum);
  else      dec_scores_body<false>(Abuf,P,enc_outs,vW,vb,Cpart,Ssum);
}

// ---------------------------------------------------------------------------
// Decoder GRU layer 0
template<bool BF>
__device__ void dec_h0_body(const float* h0in, float* h0out,
                            const float* Cpart, const float* Ssum,
                            const void* W_ih, const void* W_hh,
                            const void* b_hh, const float* gi_t)
{
  int b = blockIdx.x >> 3, q = blockIdx.x & 7;
  int tid = threadIdx.x;
  __shared__ float ctx[HH];
  __shared__ float hs[HH];
  __shared__ float red[6][256];
  const float* hr = h0in + b*HH;
  hs[tid]=hr[tid]; hs[tid+256]=hr[tid+256];
  float ssum = 0.f;
  #pragma unroll
  for(int sb=0;sb<8;sb++) ssum += Ssum[b*8+sb];
  float invS = 1.f/ssum;
  for(int j=tid;j<HH;j+=256){
    float c = 0.f;
    #pragma unroll
    for(int sb=0;sb<8;sb++) c += Cpart[((size_t)b*8+sb)*HH + j];
    ctx[j] = c*invS;
  }
  __syncthreads();
  int jj = tid>>2, t4 = tid&3, j = q*64+jj, k0 = t4*128;
  float pr=0.f,pz=0.f,pn=0.f,qr=0.f,qz=0.f,qn=0.f;
  size_t oir = (size_t)j*EHD + 64 + k0;
  size_t oiz = (size_t)(512+j)*EHD + 64 + k0;
  size_t oin = (size_t)(1024+j)*EHD + 64 + k0;
  size_t ohr = (size_t)j*HH + k0;
  size_t ohz = (size_t)(512+j)*HH + k0;
  size_t ohn = (size_t)(1024+j)*HH + k0;
  #pragma unroll 2
  for(int i=0;i<16;i++){
    float f[8];
    wload8<BF>(W_ih, oir + i*8, f);
    #pragma unroll
    for(int l=0;l<8;l++) pr += ctx[k0+i*8+l]*f[l];
    wload8<BF>(W_ih, oiz + i*8, f);
    #pragma unroll
    for(int l=0;l<8;l++) pz += ctx[k0+i*8+l]*f[l];
    wload8<BF>(W_ih, oin + i*8, f);
    #pragma unroll
    for(int l=0;l<8;l++) pn += ctx[k0+i*8+l]*f[l];
    wload8<BF>(W_hh, ohr + i*8, f);
    #pragma unroll
    for(int l=0;l<8;l++) qr += hs[k0+i*8+l]*f[l];
    wload8<BF>(W_hh, ohz + i*8, f);
    #pragma unroll
    for(int l=0;l<8;l++) qz += hs[k0+i*8+l]*f[l];
    wload8<BF>(W_hh, ohn + i*8, f);
    #pragma unroll
    for(int l=0;l<8;l++) qn += hs[k0+i*8+l]*f[l];
  }
  red[0][tid]=pr; red[1][tid]=pz; red[2][tid]=pn;
  red[3][tid]=qr; red[4][tid]=qz; red[5][tid]=qn;
  __syncthreads();
  if(t4==0){
    float gir = gi_t[b*H3 + j]        + red[0][tid]+red[0][tid+1]+red[0][tid+2]+red[0][tid+3];
    float giz = gi_t[b*H3 + 512 + j]  + red[1][tid]+red[1][tid+1]+red[1][tid+2]+red[1][tid+3];
    float gin = gi_t[b*H3 + 1024 + j] + red[2][tid]+red[2][tid+1]+red[2][tid+2]+red[2][tid+3];
    float ghr = red[3][tid]+red[3][tid+1]+red[3][tid+2]+red[3][tid+3] + wld<BF>(b_hh, j);
    float ghz = red[4][tid]+red[4][tid+1]+red[4][tid+2]+red[4][tid+3] + wld<BF>(b_hh, 512+j);
    float ghn = red[5][tid]+red[5][tid+1]+red[5][tid+2]+red[5][tid+3] + wld<BF>(b_hh, 1024+j);
    float r = sigm(gir+ghr), z = sigm(giz+ghz), n = tanh_f(gin + r*ghn);
    h0out[b*HH + j] = (1.f - z)*n + z*hs[j];
  }
}
__global__ __launch_bounds__(256) void k_dec_h0(
  const int* flag, const float* h0in, float* h0out,
  const float* Cpart, const float* Ssum,
  const void* W_ih, const void* W_hh, const void* b_hh, const float* gi_t)
{
  if(*flag) dec_h0_body<true>(h0in,h0out,Cpart,Ssum,W_ih,W_hh,b_hh,gi_t);
  else      dec_h0_body<false>(h0in,h0out,Cpart,Ssum,W_ih,W_hh,b_hh,gi_t);
}

// ---------------------------------------------------------------------------
// Decoder GRU layer 1 (+ bf16 h1 row for fc GEMM)
template<bool BF>
__device__ void dec_h1_body(const float* xin, const float* h1in, float* h1out,
                            const void* W_ih, const void* b_ih,
                            const void* W_hh, const void* b_hh,
                            u16* h1_all_t)
{
  int b = blockIdx.x >> 3, q = blockIdx.x & 7;
  int tid = threadIdx.x;
  __shared__ float xs[HH];
  __shared__ float hs[HH];
  __shared__ float red[6][256];
  const float* xr = xin + b*HH;
  const float* hr = h1in + b*HH;
  xs[tid]=xr[tid]; xs[tid+256]=xr[tid+256];
  hs[tid]=hr[tid]; hs[tid+256]=hr[tid+256];
  __syncthreads();
  int jj = tid>>2, t4 = tid&3, j = q*64+jj, k0 = t4*128;
  float pr=0.f,pz=0.f,pn=0.f,qr=0.f,qz=0.f,qn=0.f;
  size_t oir = (size_t)j*HH + k0;
  size_t oiz = (size_t)(512+j)*HH + k0;
  size_t oin = (size_t)(1024+j)*HH + k0;
  #pragma unroll 2
  for(int i=0;i<16;i++){
    float f[8];
    wload8<BF>(W_ih, oir + i*8, f);
    #pragma unroll
    for(int l=0;l<8;l++) pr += xs[k0+i*8+l]*f[l];
    wload8<BF>(W_ih, oiz + i*8, f);
    #pragma unroll
    for(int l=0;l<8;l++) pz += xs[k0+i*8+l]*f[l];
    wload8<BF>(W_ih, oin + i*8, f);
    #pragma unroll
    for(int l=0;l<8;l++) pn += xs[k0+i*8+l]*f[l];
    wload8<BF>(W_hh, oir + i*8, f);
    #pragma unroll
    for(int l=0;l<8;l++) qr += hs[k0+i*8+l]*f[l];
    wload8<BF>(W_hh, oiz + i*8, f);
    #pragma unroll
    for(int l=0;l<8;l++) qz += hs[k0+i*8+l]*f[l];
    wload8<BF>(W_hh, oin + i*8, f);
    #pragma unroll
    for(int l=0;l<8;l++) qn += hs[k0+i*8+l]*f[l];
  }
  red[0][tid]=pr; red[1][tid]=pz; red[2][tid]=pn;
  red[3][tid]=qr; red[4][tid]=qz; red[5][tid]=qn;
  __syncthreads();
  if(t4==0){
    float gir = wld<BF>(b_ih, j)      + red[0][tid]+red[0][tid+1]+red[0][tid+2]+red[0][tid+3];
    float giz = wld<BF>(b_ih, 512+j)  + red[1][tid]+red[1][tid+1]+red[1][tid+2]+red[1][tid+3];
    float gin = wld<BF>(b_ih, 1024+j) + red[2][tid]+red[2][tid+1]+red[2][tid+2]+red[2][tid+3];
    float ghr = red[3][tid]+red[3][tid+1]+red[3][tid+2]+red[3][tid+3] + wld<BF>(b_hh, j);
    float ghz = red[4][tid]+red[4][tid+1]+red[4][tid+2]+red[4][tid+3] + wld<BF>(b_hh, 512+j);
    float ghn = red[5][tid]+red[5][tid+1]+red[5][tid+2]+red[5][tid+3] + wld<BF>(b_hh, 1024+j);
    float r = sigm(gir+ghr), z = sigm(giz+ghz), n = tanh_f(gin + r*ghn);
    float hn = (1.f - z)*n + z*hs[j];
    h1out[b*HH + j] = hn;
    h1_all_t[b*HH + j] = f2bf(hn);
  }
}
__global__ __launch_bounds__(256) void k_dec_h1(
  const int* flag, const float* xin, const float* h1in, float* h1out,
  const void* W_ih, const void* b_ih, const void* W_hh, const void* b_hh,
  u16* h1_all_t)
{
  if(*flag) dec_h1_body<true>(xin,h1in,h1out,W_ih,b_ih,W_hh,b_hh,h1_all_t);
  else      dec_h1_body<false>(xin,h1in,h1out,W_ih,b_ih,W_hh,b_hh,h1_all_t);
}

// ---------------------------------------------------------------------------
// out[:, 0, :] = 0.   grid = B*V/256
__global__ __launch_bounds__(256) void k_zero_t0(const int* flag, void* out){
  int idx = blockIdx.x*256 + threadIdx.x;
  int b = idx / VV, v = idx - b*VV;
  size_t o = (size_t)b*TT*VV + v;
  if(*flag) ((u16*)out)[o] = 0;
  else      ((float*)out)[o] = 0.f;
}

// ---------------------------------------------------------------------------
// Batched fc GEMM: C[m,n] = A[m,:] . W[n,:] + b[n]; m = t*32+b -> out[b,t+1,n]
// A = h1_all [2048][512] bf16 (always ours). W = fc_W (bf16 or fp32, staged to bf16).
template<bool BF>
__device__ void fc_body(const u16* A, const void* W, const void* bias, void* out)
{
  __shared__ u16 As[128*72];   // +8 bf16 pad per row
  __shared__ u16 Bs[128*72];
  int bm = blockIdx.x, bn = blockIdx.y;
  int tid = threadIdx.x;
  int wave = tid>>6, lane = tid&63;
  int wr = wave>>1, wc = wave&1;
  f32x4 acc[4][4];
  f32x4 zero = {0.f,0.f,0.f,0.f};
  #pragma unroll
  for(int i=0;i<4;i++)
    #pragma unroll
    for(int j=0;j<4;j++) acc[i][j]=zero;

  int row = tid>>1, half = tid&1;
  const size_t gA = (size_t)(bm*128 + row)*512 + half*32;
  const size_t gB = (size_t)(bn*128 + row)*512 + half*32;
  u16* lA = As + row*72 + half*32;
  u16* lB = Bs + row*72 + half*32;

  for(int kk=0;kk<8;kk++){
    int k0 = kk*64;
    if(kk) __syncthreads();
    stage32<true>(A, gA + k0, lA);
    stage32<BF>(W, gB + k0, lB);
    __syncthreads();
    #pragma unroll
    for(int ks=0;ks<2;ks++){
      int kof = ks*32 + (lane>>4)*8;
      bf16x8 af[4], bfv[4];
      #pragma unroll
      for(int i=0;i<4;i++){
        af[i]  = *(const bf16x8*)(As + (wr*64 + i*16 + (lane&15))*72 + kof);
        bfv[i] = *(const bf16x8*)(Bs + (wc*64 + i*16 + (lane&15))*72 + kof);
      }
      #pragma unroll
      for(int i=0;i<4;i++)
        #pragma unroll
        for(int j=0;j<4;j++)
          acc[i][j] = __builtin_amdgcn_mfma_f32_16x16x32_bf16(af[i], bfv[j], acc[i][j], 0, 0, 0);
    }
  }
  // epilogue: C/D layout col = lane&15, row = (lane>>4)*4 + r   [m89-verified]
  int quad = lane>>4, col = lane&15;
  #pragma unroll
  for(int j=0;j<4;j++){
    int n = bn*128 + wc*64 + j*16 + col;
    float bsv = wld<BF>(bias, n);
    #pragma unroll
    for(int i=0;i<4;i++){
      int mbase = bm*128 + wr*64 + i*16 + quad*4;
      #pragma unroll
      for(int r=0;r<4;r++){
        int m = mbase + r;
        if(m < TD*BB){
          int t = m >> 5, b = m & 31;
          size_t o = ((size_t)(b*TT + t + 1))*VV + n;
          float v = acc[i][j][r] + bsv;
          if constexpr (BF) ((u16*)out)[o] = f2bf(v);
          else              ((float*)out)[o] = v;
        }
      }
    }
  }
}
__global__ __launch_bounds__(256) void k_fc(
  const int* flag, const u16* A, const void* W, const void* bias, void* out)
{
  if(*flag) fc_body<true>(A, W, bias, out);
  else      fc_body<false>(A, W, bias, out);
}

// ---------------------------------------------------------------------------
extern "C" void kernel_launch(void* const* d_in, const int* in_sizes, int n_in,
                              void* d_out, int out_size, void* d_ws, size_t ws_size,
                              hipStream_t stream)
{
  const int* src = (const int*)d_in[0];
  const int* trg = (const int*)d_in[1];
  const void* src_emb = d_in[2];
  const void* trg_emb = d_in[3];
  const void* eWih = d_in[4];
  const void* eWhh = d_in[5];
  const void* ebih = d_in[6];
  const void* ebhh = d_in[7];
  const void* d0Wih = d_in[8];
  const void* d0Whh = d_in[9];
  const void* d0bih = d_in[10];
  const void* d0bhh = d_in[11];
  const void* d1Wih = d_in[12];
  const void* d1Whh = d_in[13];
  const void* d1bih = d_in[14];
  const void* d1bhh = d_in[15];
  const void* aW  = d_in[16];
  const void* ab  = d_in[17];
  const void* vW  = d_in[18];
  const void* vb  = d_in[19];
  const void* fcW = d_in[20];
  const void* fcb = d_in[21];

  char* w = (char*)d_ws;
  int*   flag    = (int*)w;   w += 16;
  float* enc_gi  = (float*)w; w += (size_t)SS*BB*H3*4;   // 25.2 MB
  float* trg_gi  = (float*)w; w += (size_t)TD*BB*H3*4;   // 12.4 MB
  float* enc_outs= (float*)w; w += (size_t)BB*SS*HH*4;   // 8.4 MB
  float* P       = (float*)w; w += (size_t)BB*SS*HH*4;   // 8.4 MB
  float* hE      = (float*)w; w += (size_t)2*BB*HH*4;
  float* h0b     = (float*)w; w += (size_t)2*BB*HH*4;
  float* h1b     = (float*)w; w += (size_t)2*BB*HH*4;
  float* Abuf    = (float*)w; w += (size_t)BB*HH*4;
  float* Cpart   = (float*)w; w += (size_t)BB*8*HH*4;
  float* Ssum    = (float*)w; w += (size_t)BB*8*4;
  u16*   h1_all  = (u16*)w;   w += (size_t)MFC*HH*2;

  // init (ws is poisoned 0xAA before every call)
  hipMemsetAsync(hE, 0, BB*HH*4, stream);                        // encoder h0 = 0
  hipMemsetAsync(h1_all + (size_t)TD*BB*HH, 0, 32*HH*2, stream); // fc pad rows

  // dtype detection (writes flag)
  k_detect<<<1,64,0,stream>>>(fcW, flag);

  // batched input-gate projections
  k_emb_gi<<<SS*BB*6, 256, 0, stream>>>(flag, src, SS, src_emb, eWih, EE, ebih, enc_gi);
  k_emb_gi<<<TD*BB*6, 256, 0, stream>>>(flag, trg, TT, trg_emb, d0Wih, EHD, d0bih, trg_gi);

  // encoder recurrence
  for(int t=0;t<SS;t++){
    k_enc_step<<<256,256,0,stream>>>(
      flag, hE + (t&1)*BB*HH, hE + ((t+1)&1)*BB*HH,
      eWhh, ebhh, enc_gi + (size_t)t*BB*H3, enc_outs, t,
      (t==SS-1)?h0b:(float*)nullptr, (t==SS-1)?h1b:(float*)nullptr);
  }

  // step-invariant attention enc-projection
  k_attn_proj<<<BB*SS*2,256,0,stream>>>(flag, enc_outs, aW, ab, P);

  // decoder recurrence
  for(int t=0;t<TD;t++){
    int pi = t&1, po = (t+1)&1;
    k_dec_A<<<64,256,0,stream>>>(flag, h1b + pi*BB*HH, aW, Abuf);
    k_dec_scores<<<256,256,0,stream>>>(flag, Abuf, P, enc_outs, vW, vb, Cpart, Ssum);
    k_dec_h0<<<256,256,0,stream>>>(flag, h0b+pi*BB*HH, h0b+po*BB*HH, Cpart, Ssum,
                                   d0Wih, d0Whh, d0bhh, trg_gi + (size_t)t*BB*H3);
    k_dec_h1<<<256,256,0,stream>>>(flag, h0b+po*BB*HH, h1b+pi*BB*HH, h1b+po*BB*HH,
                                   d1Wih, d1bih, d1Whh, d1bhh, h1_all + (size_t)t*BB*HH);
  }

  // outputs
  k_zero_t0<<<(BB*VV)/256, 256, 0, stream>>>(flag, d_out);
  dim3 g(16, 250);
  k_fc<<<g, 256, 0, stream>>>(flag, h1_all, fcW, fcb, d_out);
}